// Round 7
// baseline (446.504 us; speedup 1.0000x reference)
//
#include <hip/hip_runtime.h>
#include <math.h>

#define NB 4
#define NL 2048
#define NH 8
#define ND 64
#define NUPART 80
#define NUTOP 40
#define NBLK 512                  // persistent grid: 2 blocks/CU on 256 CUs
#define NROWS (NB * NH * NL)      // 65536 output rows
#define NATTN (NB * NH * NUTOP)   // 1280 selected rows
#define Z1ROWS 20480              // phase A zero rows (160 MiB) -- hides M
#define Z2ROWS 2048               // phase C zero rows (16 MiB)  -- hides topk
#define Z3BASE (Z1ROWS + Z2ROWS)  // 22528
#define Z3ROWS (NROWS - Z3BASE)   // 43008 = 84 per block -- hides attn

typedef float vfloat4 __attribute__((ext_vector_type(4)));

__device__ __forceinline__ void zero_row(float* __restrict__ out, int r, int t) {
    vfloat4* o = (vfloat4*)out + (size_t)r * (NL / 4) + t;
    const vfloat4 z = (vfloat4)(0.0f);
    o[0]   = z;
    o[256] = z;
}

// Device-scope sense barrier. All NBLK blocks are co-resident
// (__launch_bounds__(256,2) => 2 blocks/CU guaranteed). __threadfence()
// (agent-scope fence) performs the L2 writeback/invalidate needed for
// cross-XCD visibility of M / rowmap / Mtop.
__device__ __forceinline__ void gbar(int* cnt, int* gen, int target) {
    __syncthreads();
    if (threadIdx.x == 0) {
        __threadfence();
        if (atomicAdd(cnt, 1) == NBLK - 1) {
            atomicExch(cnt, 0);
            __threadfence();
            atomicExch(gen, target);
        } else {
            while (__hip_atomic_load(gen, __ATOMIC_RELAXED,
                                     __HIP_MEMORY_SCOPE_AGENT) < target) {
                __builtin_amdgcn_s_sleep(8);
            }
        }
        __threadfence();
    }
    __syncthreads();
}

__global__ __launch_bounds__(256, 2) void k_fused(
    const float* __restrict__ q, const float* __restrict__ k,
    const int* __restrict__ idx, float* __restrict__ M,
    int* __restrict__ rowmap, int* __restrict__ Mtop,
    int* __restrict__ bar, float* __restrict__ out)
{
    __shared__ float sM[NL];
    __shared__ float rv[4];
    __shared__ int   ri[4];
    __shared__ float redm[4];
    __shared__ float reds[4];

    const int t    = threadIdx.x;
    const int bid  = blockIdx.x;
    const int wid  = t >> 6;
    const int lane = t & 63;

    // =========== Phase A: M for 65536 rows (32 tasks/wave) + zone-1 zeros ==
    {
        const int gw = bid * 4 + wid;        // global wave id in [0,2048)
        const int sl = lane >> 2;            // sample slot 0..15
        const int dg = lane & 3;             // d-group 0..3
        const int d0 = dg * 16;

        for (int j = 0; j < 40; ++j) {
            if (j < 32) {
                const int w  = gw + 2048 * j;        // row id (b*H+h)*L + l
                const int l  = w & (NL - 1);
                const int bh = w >> 11;
                const int h  = bh & (NH - 1);
                const int b  = bh >> 3;

                const float4* qv = (const float4*)(q + (((size_t)(b * NL + l) * NH + h) * ND + d0));
                const float4 q0 = qv[0], q1 = qv[1], q2 = qv[2], q3 = qv[3];

                float mx = -INFINITY, sm = 0.0f;
#pragma unroll
                for (int r = 0; r < 5; ++r) {
                    const int s  = r * 16 + sl;
                    const int ki = idx[l * NUPART + s];
                    const float4* kv = (const float4*)(k + (((size_t)(b * NL + ki) * NH + h) * ND + d0));
                    const float4 k0 = kv[0], k1 = kv[1], k2 = kv[2], k3 = kv[3];
                    float p = q0.x * k0.x + q0.y * k0.y + q0.z * k0.z + q0.w * k0.w
                            + q1.x * k1.x + q1.y * k1.y + q1.z * k1.z + q1.w * k1.w
                            + q2.x * k2.x + q2.y * k2.y + q2.z * k2.z + q2.w * k2.w
                            + q3.x * k3.x + q3.y * k3.y + q3.z * k3.z + q3.w * k3.w;
                    p += __shfl_xor(p, 1);
                    p += __shfl_xor(p, 2);
                    mx = fmaxf(mx, p);
                    sm += p;
                }
#pragma unroll
                for (int m = 4; m < 64; m <<= 1) {
                    mx = fmaxf(mx, __shfl_xor(mx, m));
                    sm += __shfl_xor(sm, m);
                }
                if (lane == 0) M[w] = mx - sm * (1.0f / (float)NL);
            }
            zero_row(out, j * NBLK + bid, t);      // zone 1: rows [0, 20480)
        }
    }

    gbar(bar, bar + 1, 1);

    // =========== Phase C: blocks 0..31 topk(bh) ; others zone-2 zeros ======
    if (bid < NB * NH) {
        const int bh = bid;
        for (int j = t; j < NL; j += 256) {
            sM[j] = M[bh * NL + j];
            rowmap[bh * NL + j] = 0;
        }
        __syncthreads();

        for (int it = 0; it < NUTOP; ++it) {
            float v = -INFINITY;
            int   i = NL;
            for (int j = t; j < NL; j += 256) {
                const float m = sM[j];
                if (m > v || (m == v && j < i)) { v = m; i = j; }
            }
#pragma unroll
            for (int off = 1; off < 64; off <<= 1) {
                const float ov = __shfl_xor(v, off);
                const int   oi = __shfl_xor(i, off);
                if (ov > v || (ov == v && oi < i)) { v = ov; i = oi; }
            }
            if ((t & 63) == 0) { rv[wid] = v; ri[wid] = i; }
            __syncthreads();
            if (t == 0) {
                for (int w2 = 1; w2 < 4; ++w2) {
                    if (rv[w2] > v || (rv[w2] == v && ri[w2] < i)) { v = rv[w2]; i = ri[w2]; }
                }
                Mtop[bh * NUTOP + it] = i;
                rowmap[bh * NL + i] = 1;
                sM[i] = -INFINITY;
            }
            __syncthreads();
        }
    } else {
        for (int r2 = bid - NB * NH; r2 < Z2ROWS; r2 += NBLK - NB * NH)
            zero_row(out, Z1ROWS + r2, t);         // zone 2: rows [20480, 22528)
    }

    gbar(bar, bar + 1, 2);

    // =========== Phase D: zone-3 zeros (skip selected) + attn interleaved ==
    {
        int a = bid;                                // attn task ids: bid, +512, +1024
        for (int j = 0; j < Z3ROWS / NBLK; ++j) {   // 84 rows per block
            if ((j % 28) == 14 && a < NATTN) {
                // ---- attn task: one selected row ----
                const int bh  = a / NUTOP;
                const int ui  = a % NUTOP;
                const int b   = bh >> 3;
                const int h   = bh & 7;
                const int row = Mtop[bh * NUTOP + ui];

                const float4* qv = (const float4*)(q + (((size_t)(b * NL + row)) * NH + h) * ND);
                float4 qr[16];
#pragma unroll
                for (int i = 0; i < 16; ++i) qr[i] = qv[i];

                float sc[8];
                float mx = -INFINITY;
#pragma unroll
                for (int jj = 0; jj < 8; ++jj) {
                    const int l = t + 256 * jj;
                    const float4* kv = (const float4*)(k + (((size_t)(b * NL + l)) * NH + h) * ND);
                    float s = 0.0f;
#pragma unroll
                    for (int i = 0; i < 16; ++i) {
                        const float4 kk = kv[i];
                        s += qr[i].x * kk.x + qr[i].y * kk.y + qr[i].z * kk.z + qr[i].w * kk.w;
                    }
                    sc[jj] = s * 0.125f;   // 1/sqrt(64)
                    mx = fmaxf(mx, sc[jj]);
                }
#pragma unroll
                for (int off = 1; off < 64; off <<= 1) mx = fmaxf(mx, __shfl_xor(mx, off));
                if (lane == 0) redm[wid] = mx;
                __syncthreads();
                mx = fmaxf(fmaxf(redm[0], redm[1]), fmaxf(redm[2], redm[3]));

                float lsum = 0.0f;
#pragma unroll
                for (int jj = 0; jj < 8; ++jj) {
                    sc[jj] = __expf(sc[jj] - mx);
                    lsum += sc[jj];
                }
#pragma unroll
                for (int off = 1; off < 64; off <<= 1) lsum += __shfl_xor(lsum, off);
                if (lane == 0) reds[wid] = lsum;
                __syncthreads();
                const float inv = 1.0f / (reds[0] + reds[1] + reds[2] + reds[3]);

                float* orow = out + ((size_t)bh * NL + row) * NL;
#pragma unroll
                for (int jj = 0; jj < 8; ++jj) orow[t + 256 * jj] = sc[jj] * inv;

                a += NBLK;
                __syncthreads();
            }
            const int r = Z3BASE + j * NBLK + bid;  // zone 3: rows [22528, 65536)
            if (!rowmap[r]) zero_row(out, r, t);
        }
    }
}

extern "C" void kernel_launch(void* const* d_in, const int* in_sizes, int n_in,
                              void* d_out, int out_size, void* d_ws, size_t ws_size,
                              hipStream_t stream) {
    const float* q   = (const float*)d_in[0];
    const float* k   = (const float*)d_in[1];
    const int*   idx = (const int*)d_in[2];
    float* out = (float*)d_out;

    float* Mws    = (float*)d_ws;                                  // 65536 f (256 KiB)
    int*   rowmap = (int*)((char*)d_ws + (256 << 10));             // 65536 i (256 KiB)
    int*   Mtop   = (int*)((char*)d_ws + (512 << 10));             // 1280 i
    int*   bar    = (int*)((char*)d_ws + (520 << 10));             // {cnt, gen}

    hipMemsetAsync(bar, 0, 2 * sizeof(int), stream);               // reset barrier
    k_fused<<<NBLK, 256, 0, stream>>>(q, k, idx, Mws, rowmap, Mtop, bar, out);
}

// Round 8
// 404.677 us; speedup vs baseline: 1.1034x; 1.1034x over previous
//
#include <hip/hip_runtime.h>
#include <math.h>

#define NB 4
#define NL 2048
#define NH 8
#define ND 64
#define NUPART 80
#define NUTOP 40
#define NMBLK 2048                 // M-compute blocks (8192 waves x 8 rows)
#define NZBLK 16384                // zero-only blocks (32 KiB slice each)
#define NATTN (NB * NH * NUTOP)    // 1280 selected rows

typedef float vfloat4 __attribute__((ext_vector_type(4)));

// ---------------------------------------------------------------------------
// K1 heterogeneous: blocks [0,2048) compute M (one wave = 8 rows, 80-sample
// gather-dot each); blocks [2048, 18432) zero the ENTIRE 512 MiB output in
// contiguous 32 KiB slices, memset-style (stores only -- no reads, no VALU
// in the issue stream), so the write tide runs at the d_out cap while the
// latency-bound M gathers hide on concurrently-resident waves.
// ---------------------------------------------------------------------------
__global__ __launch_bounds__(256) void k_zero_M(
    const float* __restrict__ q, const float* __restrict__ k,
    const int* __restrict__ idx, float* __restrict__ M,
    float* __restrict__ out)
{
    const int t = threadIdx.x;

    if (blockIdx.x >= NMBLK) {
        // ---- zero-only block: 2048 float4 = 32 KiB contiguous slice ----
        const int zb = blockIdx.x - NMBLK;
        vfloat4* o = (vfloat4*)out + (size_t)zb * 2048 + t;
        const vfloat4 z = (vfloat4)(0.0f);
#pragma unroll
        for (int i = 0; i < 8; ++i) o[i * 256] = z;
        return;
    }

    // ---- M block: one wave per 8 rows ----
    const int wid  = t >> 6;
    const int lane = t & 63;
    const int gw   = blockIdx.x * 4 + wid;   // [0, 8192)
    const int sl   = lane >> 2;              // sample slot 0..15
    const int dg   = lane & 3;               // d-group 0..3
    const int d0   = dg * 16;

    for (int j = 0; j < 8; ++j) {
        const int w  = gw + 8192 * j;        // row id (b*H+h)*L + l
        const int l  = w & (NL - 1);
        const int bh = w >> 11;
        const int h  = bh & (NH - 1);
        const int b  = bh >> 3;

        const float4* qv = (const float4*)(q + (((size_t)(b * NL + l) * NH + h) * ND + d0));
        const float4 q0 = qv[0], q1 = qv[1], q2 = qv[2], q3 = qv[3];

        float mx = -INFINITY, sm = 0.0f;
#pragma unroll
        for (int r = 0; r < 5; ++r) {
            const int s  = r * 16 + sl;
            const int ki = idx[l * NUPART + s];
            const float4* kv = (const float4*)(k + (((size_t)(b * NL + ki) * NH + h) * ND + d0));
            const float4 k0 = kv[0], k1 = kv[1], k2 = kv[2], k3 = kv[3];
            float p = q0.x * k0.x + q0.y * k0.y + q0.z * k0.z + q0.w * k0.w
                    + q1.x * k1.x + q1.y * k1.y + q1.z * k1.z + q1.w * k1.w
                    + q2.x * k2.x + q2.y * k2.y + q2.z * k2.z + q2.w * k2.w
                    + q3.x * k3.x + q3.y * k3.y + q3.z * k3.z + q3.w * k3.w;
            p += __shfl_xor(p, 1);
            p += __shfl_xor(p, 2);
            mx = fmaxf(mx, p);
            sm += p;
        }
#pragma unroll
        for (int m = 4; m < 64; m <<= 1) {
            mx = fmaxf(mx, __shfl_xor(mx, m));
            sm += __shfl_xor(sm, m);
        }
        if (lane == 0) M[w] = mx - sm * (1.0f / (float)NL);
    }
}

// ---------------------------------------------------------------------------
// K2: per (b,h), top-40 of 2048 M values (iterative argmax, lower index
// wins ties -- matches jax.lax.top_k selection set). Emits Mtop only.
// ---------------------------------------------------------------------------
__global__ __launch_bounds__(256) void k_topk(
    const float* __restrict__ M, int* __restrict__ Mtop)
{
    __shared__ float sM[NL];
    __shared__ float rv[4];
    __shared__ int   ri[4];
    const int bh = blockIdx.x;
    const int t  = threadIdx.x;

    for (int j = t; j < NL; j += 256) sM[j] = M[bh * NL + j];
    __syncthreads();

    for (int it = 0; it < NUTOP; ++it) {
        float v = -INFINITY;
        int   i = NL;
        for (int j = t; j < NL; j += 256) {
            const float m = sM[j];
            if (m > v || (m == v && j < i)) { v = m; i = j; }
        }
#pragma unroll
        for (int off = 1; off < 64; off <<= 1) {
            const float ov = __shfl_xor(v, off);
            const int   oi = __shfl_xor(i, off);
            if (ov > v || (ov == v && oi < i)) { v = ov; i = oi; }
        }
        const int wid = t >> 6;
        if ((t & 63) == 0) { rv[wid] = v; ri[wid] = i; }
        __syncthreads();
        if (t == 0) {
            for (int w2 = 1; w2 < 4; ++w2) {
                if (rv[w2] > v || (rv[w2] == v && ri[w2] < i)) { v = rv[w2]; i = ri[w2]; }
            }
            Mtop[bh * NUTOP + it] = i;
            sM[i] = -INFINITY;
        }
        __syncthreads();
    }
}

// ---------------------------------------------------------------------------
// K3: attn-only. One block per selected row: q_row.K^T -> softmax ->
// overwrite the (already-zeroed) 2048-wide output row. No flags, no skips.
// ---------------------------------------------------------------------------
__global__ __launch_bounds__(256) void k_attn(
    const float* __restrict__ q, const float* __restrict__ k,
    const int* __restrict__ Mtop, float* __restrict__ out)
{
    __shared__ float redm[4];
    __shared__ float reds[4];

    const int bh  = blockIdx.x / NUTOP;
    const int ui  = blockIdx.x % NUTOP;
    const int b   = bh >> 3;
    const int h   = bh & 7;
    const int row = Mtop[bh * NUTOP + ui];
    const int t   = threadIdx.x;
    const int lane = t & 63;
    const int wid  = t >> 6;

    // q row is wave-uniform: broadcast loads, kept in registers
    const float4* qv = (const float4*)(q + (((size_t)(b * NL + row)) * NH + h) * ND);
    float4 qr[16];
#pragma unroll
    for (int i = 0; i < 16; ++i) qr[i] = qv[i];

    float sc[8];
    float mx = -INFINITY;
#pragma unroll
    for (int j = 0; j < 8; ++j) {
        const int l = t + 256 * j;
        const float4* kv = (const float4*)(k + (((size_t)(b * NL + l)) * NH + h) * ND);
        float s = 0.0f;
#pragma unroll
        for (int i = 0; i < 16; ++i) {
            const float4 kk = kv[i];
            s += qr[i].x * kk.x + qr[i].y * kk.y + qr[i].z * kk.z + qr[i].w * kk.w;
        }
        sc[j] = s * 0.125f;   // 1/sqrt(64)
        mx = fmaxf(mx, sc[j]);
    }

#pragma unroll
    for (int off = 1; off < 64; off <<= 1) mx = fmaxf(mx, __shfl_xor(mx, off));
    if (lane == 0) redm[wid] = mx;
    __syncthreads();
    mx = fmaxf(fmaxf(redm[0], redm[1]), fmaxf(redm[2], redm[3]));

    float lsum = 0.0f;
#pragma unroll
    for (int j = 0; j < 8; ++j) {
        sc[j] = __expf(sc[j] - mx);
        lsum += sc[j];
    }
#pragma unroll
    for (int off = 1; off < 64; off <<= 1) lsum += __shfl_xor(lsum, off);
    if (lane == 0) reds[wid] = lsum;
    __syncthreads();
    const float inv = 1.0f / (reds[0] + reds[1] + reds[2] + reds[3]);

    float* orow = out + ((size_t)bh * NL + row) * NL;
#pragma unroll
    for (int j = 0; j < 8; ++j) {
        orow[t + 256 * j] = sc[j] * inv;
    }
}

extern "C" void kernel_launch(void* const* d_in, const int* in_sizes, int n_in,
                              void* d_out, int out_size, void* d_ws, size_t ws_size,
                              hipStream_t stream) {
    const float* q   = (const float*)d_in[0];
    const float* k   = (const float*)d_in[1];
    const int*   idx = (const int*)d_in[2];
    float* out = (float*)d_out;

    float* Mws  = (float*)d_ws;                                   // 65536 f
    int*   Mtop = (int*)((char*)d_ws + (size_t)NB * NH * NL * 4); // 1280 i

    k_zero_M<<<NMBLK + NZBLK, 256, 0, stream>>>(q, k, idx, Mws, out);
    k_topk<<<NB * NH, 256, 0, stream>>>(Mws, Mtop);
    k_attn<<<NATTN, 256, 0, stream>>>(q, k, Mtop, out);
}

// Round 9
// 345.067 us; speedup vs baseline: 1.2940x; 1.1727x over previous
//
#include <hip/hip_runtime.h>
#include <math.h>

#define NB 4
#define NL 2048
#define NH 8
#define ND 64
#define NUPART 80
#define NUTOP 40
#define NROWS (NB * NH * NL)       // 65536 output rows
#define NATTN (NB * NH * NUTOP)    // 1280 selected rows
#define Z1ROWS 12288               // rows [0,12288) zeroed by K1 (96 MiB)
#define NZ3 (NROWS - Z1ROWS)       // 53248 rows zeroed by K3b (416 MiB)
#define K3BLK (NZ3 / 4)            // 13312 blocks, 4 rows each

typedef float vfloat4 __attribute__((ext_vector_type(4)));

__device__ __forceinline__ void zero_row(float* __restrict__ out, int r, int t) {
    vfloat4* o = (vfloat4*)out + (size_t)r * (NL / 4) + t;
    const vfloat4 z = (vfloat4)(0.0f);
    o[0]   = z;
    o[256] = z;
}

// ---------------------------------------------------------------------------
// K1: same-wave fused (the proven R5 shape): one wave per (b,h,l) computes
// M = max - sum/L over 80 sampled keys; each block also zeroes a contiguous
// 6 KiB slice of rows [0,12288) -- sized so the zero tide (~60 us at the
// ~1.6 TB/s d_out cap) just covers the gather-bound M compute.
// ---------------------------------------------------------------------------
__global__ __launch_bounds__(256) void k_compute_M_zero(
    const float* __restrict__ q, const float* __restrict__ k,
    const int* __restrict__ idx, float* __restrict__ M,
    float* __restrict__ out)
{
    const int t = threadIdx.x;

    // ---- zero slice: 384 float4 per block (16384 * 384 = rows [0,12288)) --
    {
        vfloat4* o = (vfloat4*)out + (size_t)blockIdx.x * 384 + t;
        const vfloat4 z = (vfloat4)(0.0f);
        o[0] = z;
        if (t < 128) o[256] = z;
    }

    // ---- M computation: one wave per (b,h,l) ----
    const int w    = blockIdx.x * 4 + (t >> 6);   // (b*H+h)*L + l
    const int lane = t & 63;
    const int l    = w & (NL - 1);
    const int bh   = w >> 11;
    const int h    = bh & (NH - 1);
    const int b    = bh >> 3;
    const int sl   = lane >> 2;   // sample slot 0..15
    const int dg   = lane & 3;    // d-group 0..3
    const int d0   = dg * 16;

    const float4* qv = (const float4*)(q + (((size_t)(b * NL + l) * NH + h) * ND + d0));
    const float4 q0 = qv[0], q1 = qv[1], q2 = qv[2], q3 = qv[3];

    float mx = -INFINITY, sm = 0.0f;
#pragma unroll
    for (int r = 0; r < 5; ++r) {
        const int s  = r * 16 + sl;
        const int ki = idx[l * NUPART + s];
        const float4* kv = (const float4*)(k + (((size_t)(b * NL + ki) * NH + h) * ND + d0));
        const float4 k0 = kv[0], k1 = kv[1], k2 = kv[2], k3 = kv[3];
        float p = q0.x * k0.x + q0.y * k0.y + q0.z * k0.z + q0.w * k0.w
                + q1.x * k1.x + q1.y * k1.y + q1.z * k1.z + q1.w * k1.w
                + q2.x * k2.x + q2.y * k2.y + q2.z * k2.z + q2.w * k2.w
                + q3.x * k3.x + q3.y * k3.y + q3.z * k3.z + q3.w * k3.w;
        p += __shfl_xor(p, 1);
        p += __shfl_xor(p, 2);
        mx = fmaxf(mx, p);
        sm += p;
    }
#pragma unroll
    for (int m = 4; m < 64; m <<= 1) {
        mx = fmaxf(mx, __shfl_xor(mx, m));
        sm += __shfl_xor(sm, m);
    }
    if (lane == 0) M[w] = mx - sm * (1.0f / (float)NL);
}

// ---------------------------------------------------------------------------
// K2: per (b,h), top-40 of 2048 M values (iterative argmax, lower index
// wins ties). Emits Mtop and the per-row selected flag (rowmap).
// ---------------------------------------------------------------------------
__global__ __launch_bounds__(256) void k_topk(
    const float* __restrict__ M, int* __restrict__ rowmap,
    int* __restrict__ Mtop)
{
    __shared__ float sM[NL];
    __shared__ float rv[4];
    __shared__ int   ri[4];
    const int bh = blockIdx.x;
    const int t  = threadIdx.x;

    for (int j = t; j < NL; j += 256) {
        sM[j] = M[bh * NL + j];
        rowmap[bh * NL + j] = 0;
    }
    __syncthreads();

    for (int it = 0; it < NUTOP; ++it) {
        float v = -INFINITY;
        int   i = NL;
        for (int j = t; j < NL; j += 256) {
            const float m = sM[j];
            if (m > v || (m == v && j < i)) { v = m; i = j; }
        }
#pragma unroll
        for (int off = 1; off < 64; off <<= 1) {
            const float ov = __shfl_xor(v, off);
            const int   oi = __shfl_xor(i, off);
            if (ov > v || (ov == v && oi < i)) { v = ov; i = oi; }
        }
        const int wid = t >> 6;
        if ((t & 63) == 0) { rv[wid] = v; ri[wid] = i; }
        __syncthreads();
        if (t == 0) {
            for (int w2 = 1; w2 < 4; ++w2) {
                if (rv[w2] > v || (rv[w2] == v && ri[w2] < i)) { v = rv[w2]; i = ri[w2]; }
            }
            Mtop[bh * NUTOP + it] = i;
            rowmap[bh * NL + i] = 1;
            sM[i] = -INFINITY;
        }
        __syncthreads();
    }
}

// ---------------------------------------------------------------------------
// K3a: scores. 256 blocks = 32 bh x 8 column-tiles. The 40 selected q-rows
// are staged in LDS (10 KiB, broadcast reads); each thread owns one K
// column (16 float4 in registers) and computes 40 dots. K is read ONCE per
// bh (16 MB total vs 640 MB in the per-row scheme). Raw scaled scores go
// to d_ws (fast buffer), 10.5 MB.
// ---------------------------------------------------------------------------
__global__ __launch_bounds__(256) void k_scores(
    const float* __restrict__ q, const float* __restrict__ k,
    const int* __restrict__ Mtop, float* __restrict__ scores)
{
    __shared__ float4 qs[NUTOP][16];
    __shared__ int    rows[NUTOP];

    const int bh = blockIdx.x >> 3;
    const int ct = blockIdx.x & 7;
    const int b  = bh >> 3;
    const int h  = bh & 7;
    const int t  = threadIdx.x;

    if (t < NUTOP) rows[t] = Mtop[bh * NUTOP + t];
    __syncthreads();
    for (int i = t; i < NUTOP * 16; i += 256) {
        const int r = i >> 4, d = i & 15;
        qs[r][d] = ((const float4*)q)[((size_t)(b * NL + rows[r]) * NH + h) * 16 + d];
    }
    __syncthreads();

    const int c = ct * 256 + t;
    const float4* kv = (const float4*)k + ((size_t)(b * NL + c) * NH + h) * 16;
    float4 kc[16];
#pragma unroll
    for (int i = 0; i < 16; ++i) kc[i] = kv[i];

    float* srow = scores + (size_t)bh * NUTOP * NL + c;
    for (int r = 0; r < NUTOP; ++r) {
        float s = 0.0f;
#pragma unroll
        for (int i = 0; i < 16; ++i) {
            const float4 qq = qs[r][i];
            s += qq.x * kc[i].x + qq.y * kc[i].y + qq.z * kc[i].z + qq.w * kc[i].w;
        }
        srow[(size_t)r * NL] = s * 0.125f;   // 1/sqrt(64)
    }
}

// ---------------------------------------------------------------------------
// K3b: the main write tide. 13312 blocks zero 4 rows each of [12288,65536)
// (skipping selected rows via rowmap); the first 1280 blocks additionally
// normalize one attn row: read its 2048 raw scores from ws (8 KiB, L2),
// block softmax, write the row. The light attn epilogue hides inside the
// 416 MiB zero stream.
// ---------------------------------------------------------------------------
__global__ __launch_bounds__(256) void k_zero_attn(
    const int* __restrict__ rowmap, const int* __restrict__ Mtop,
    const float* __restrict__ scores, float* __restrict__ out)
{
    const int t = threadIdx.x;

    // ---- zero duty: 4 rows ----
    {
        const int r0 = Z1ROWS + blockIdx.x * 4;
#pragma unroll
        for (int rr = 0; rr < 4; ++rr) {
            const int r = r0 + rr;
            if (!rowmap[r]) zero_row(out, r, t);
        }
    }

    // ---- attn duty for the first NATTN blocks ----
    if (blockIdx.x < NATTN) {
        __shared__ float redm[4];
        __shared__ float reds[4];
        const int a    = blockIdx.x;
        const int bh   = a / NUTOP;
        const int ui   = a % NUTOP;
        const int row  = Mtop[bh * NUTOP + ui];
        const int lane = t & 63;
        const int wid  = t >> 6;

        const float* srow = scores + ((size_t)bh * NUTOP + ui) * NL;
        float sc[8];
        float mx = -INFINITY;
#pragma unroll
        for (int j = 0; j < 8; ++j) {
            sc[j] = srow[t + 256 * j];
            mx = fmaxf(mx, sc[j]);
        }
#pragma unroll
        for (int off = 1; off < 64; off <<= 1) mx = fmaxf(mx, __shfl_xor(mx, off));
        if (lane == 0) redm[wid] = mx;
        __syncthreads();
        mx = fmaxf(fmaxf(redm[0], redm[1]), fmaxf(redm[2], redm[3]));

        float lsum = 0.0f;
#pragma unroll
        for (int j = 0; j < 8; ++j) {
            sc[j] = __expf(sc[j] - mx);
            lsum += sc[j];
        }
#pragma unroll
        for (int off = 1; off < 64; off <<= 1) lsum += __shfl_xor(lsum, off);
        if (lane == 0) reds[wid] = lsum;
        __syncthreads();
        const float inv = 1.0f / (reds[0] + reds[1] + reds[2] + reds[3]);

        float* orow = out + ((size_t)bh * NL + row) * NL;
#pragma unroll
        for (int j = 0; j < 8; ++j) orow[t + 256 * j] = sc[j] * inv;
    }
}

extern "C" void kernel_launch(void* const* d_in, const int* in_sizes, int n_in,
                              void* d_out, int out_size, void* d_ws, size_t ws_size,
                              hipStream_t stream) {
    const float* q   = (const float*)d_in[0];
    const float* k   = (const float*)d_in[1];
    const int*   idx = (const int*)d_in[2];
    float* out = (float*)d_out;

    float* Mws    = (float*)d_ws;                               // @0       256 KiB
    int*   rowmap = (int*)((char*)d_ws + (256 << 10));          // @256 KiB 256 KiB
    int*   Mtop   = (int*)((char*)d_ws + (512 << 10));          // @512 KiB   5 KiB
    float* scores = (float*)((char*)d_ws + (1 << 20));          // @1 MiB    10 MiB

    k_compute_M_zero<<<NROWS / 4, 256, 0, stream>>>(q, k, idx, Mws, out);
    k_topk<<<NB * NH, 256, 0, stream>>>(Mws, rowmap, Mtop);
    k_scores<<<NB * NH * 8, 256, 0, stream>>>(q, k, Mtop, scores);
    k_zero_attn<<<K3BLK, 256, 0, stream>>>(rowmap, Mtop, scores, out);
}

// Round 10
// 340.106 us; speedup vs baseline: 1.3128x; 1.0146x over previous
//
#include <hip/hip_runtime.h>
#include <math.h>

#define NB 4
#define NL 2048
#define NH 8
#define ND 64
#define NUPART 80
#define NUTOP 40
#define NROWS (NB * NH * NL)       // 65536 output rows
#define NATTN (NB * NH * NUTOP)    // 1280 selected rows
#define Z1ROWS 12288               // rows [0,12288) zeroed by K1 (96 MiB)
#define NZ3 (NROWS - Z1ROWS)       // 53248 rows zeroed by K3b (416 MiB)
#define K3BLK (NZ3 / 4)            // 13312 blocks
#define Z1F4 (Z1ROWS * 512)        // 6,291,456 float4 in zone 1
#define G1 (16384 * 256)           // K1 grid threads = 4,194,304
#define Z3F4 (NZ3 * 512)           // 27,262,976 float4 in zone 3
#define G3 (K3BLK * 256)           // K3b grid threads = 3,407,872 (multiple of 512)

typedef float vfloat4 __attribute__((ext_vector_type(4)));

// ---------------------------------------------------------------------------
// K1: same-wave fused: one wave per (b,h,l) computes M = max - sum/L over 80
// sampled keys; the zero duty for rows [0,12288) is GRID-STRIDED (the rocclr
// fill pattern that achieves 1.68 TB/s on this buffer), 1-2 stores/thread.
// ---------------------------------------------------------------------------
__global__ __launch_bounds__(256) void k_compute_M_zero(
    const float* __restrict__ q, const float* __restrict__ k,
    const int* __restrict__ idx, float* __restrict__ M,
    float* __restrict__ out)
{
    const int t = threadIdx.x;

    // ---- zero duty: grid-stride over zone-1 float4s ----
    {
        const int g = blockIdx.x * 256 + t;
        vfloat4* o = (vfloat4*)out;
        const vfloat4 z = (vfloat4)(0.0f);
        o[g] = z;
        const int g2 = g + G1;
        if (g2 < Z1F4) o[g2] = z;
    }

    // ---- M computation: one wave per (b,h,l) ----
    const int w    = blockIdx.x * 4 + (t >> 6);   // (b*H+h)*L + l
    const int lane = t & 63;
    const int l    = w & (NL - 1);
    const int bh   = w >> 11;
    const int h    = bh & (NH - 1);
    const int b    = bh >> 3;
    const int sl   = lane >> 2;   // sample slot 0..15
    const int dg   = lane & 3;    // d-group 0..3
    const int d0   = dg * 16;

    const float4* qv = (const float4*)(q + (((size_t)(b * NL + l) * NH + h) * ND + d0));
    const float4 q0 = qv[0], q1 = qv[1], q2 = qv[2], q3 = qv[3];

    float mx = -INFINITY, sm = 0.0f;
#pragma unroll
    for (int r = 0; r < 5; ++r) {
        const int s  = r * 16 + sl;
        const int ki = idx[l * NUPART + s];
        const float4* kv = (const float4*)(k + (((size_t)(b * NL + ki) * NH + h) * ND + d0));
        const float4 k0 = kv[0], k1 = kv[1], k2 = kv[2], k3 = kv[3];
        float p = q0.x * k0.x + q0.y * k0.y + q0.z * k0.z + q0.w * k0.w
                + q1.x * k1.x + q1.y * k1.y + q1.z * k1.z + q1.w * k1.w
                + q2.x * k2.x + q2.y * k2.y + q2.z * k2.z + q2.w * k2.w
                + q3.x * k3.x + q3.y * k3.y + q3.z * k3.z + q3.w * k3.w;
        p += __shfl_xor(p, 1);
        p += __shfl_xor(p, 2);
        mx = fmaxf(mx, p);
        sm += p;
    }
#pragma unroll
    for (int m = 4; m < 64; m <<= 1) {
        mx = fmaxf(mx, __shfl_xor(mx, m));
        sm += __shfl_xor(sm, m);
    }
    if (lane == 0) M[w] = mx - sm * (1.0f / (float)NL);
}

// ---------------------------------------------------------------------------
// K2: per (b,h), top-40 of 2048 M values (iterative argmax, lower index
// wins ties). Emits Mtop and the per-row selected flag (rowmap).
// ---------------------------------------------------------------------------
__global__ __launch_bounds__(256) void k_topk(
    const float* __restrict__ M, int* __restrict__ rowmap,
    int* __restrict__ Mtop)
{
    __shared__ float sM[NL];
    __shared__ float rv[4];
    __shared__ int   ri[4];
    const int bh = blockIdx.x;
    const int t  = threadIdx.x;

    for (int j = t; j < NL; j += 256) {
        sM[j] = M[bh * NL + j];
        rowmap[bh * NL + j] = 0;
    }
    __syncthreads();

    for (int it = 0; it < NUTOP; ++it) {
        float v = -INFINITY;
        int   i = NL;
        for (int j = t; j < NL; j += 256) {
            const float m = sM[j];
            if (m > v || (m == v && j < i)) { v = m; i = j; }
        }
#pragma unroll
        for (int off = 1; off < 64; off <<= 1) {
            const float ov = __shfl_xor(v, off);
            const int   oi = __shfl_xor(i, off);
            if (ov > v || (ov == v && oi < i)) { v = ov; i = oi; }
        }
        const int wid = t >> 6;
        if ((t & 63) == 0) { rv[wid] = v; ri[wid] = i; }
        __syncthreads();
        if (t == 0) {
            for (int w2 = 1; w2 < 4; ++w2) {
                if (rv[w2] > v || (rv[w2] == v && ri[w2] < i)) { v = rv[w2]; i = ri[w2]; }
            }
            Mtop[bh * NUTOP + it] = i;
            rowmap[bh * NL + i] = 1;
            sM[i] = -INFINITY;
        }
        __syncthreads();
    }
}

// ---------------------------------------------------------------------------
// K3a: scores. 256 blocks = 32 bh x 8 column-tiles. 40 selected q-rows in
// LDS; each thread owns one K column (16 float4 in regs), 40 dots. K read
// ONCE per bh. Raw scaled scores to d_ws (10.5 MB).
// ---------------------------------------------------------------------------
__global__ __launch_bounds__(256) void k_scores(
    const float* __restrict__ q, const float* __restrict__ k,
    const int* __restrict__ Mtop, float* __restrict__ scores)
{
    __shared__ float4 qs[NUTOP][16];
    __shared__ int    rows[NUTOP];

    const int bh = blockIdx.x >> 3;
    const int ct = blockIdx.x & 7;
    const int b  = bh >> 3;
    const int h  = bh & 7;
    const int t  = threadIdx.x;

    if (t < NUTOP) rows[t] = Mtop[bh * NUTOP + t];
    __syncthreads();
    for (int i = t; i < NUTOP * 16; i += 256) {
        const int r = i >> 4, d = i & 15;
        qs[r][d] = ((const float4*)q)[((size_t)(b * NL + rows[r]) * NH + h) * 16 + d];
    }
    __syncthreads();

    const int c = ct * 256 + t;
    const float4* kv = (const float4*)k + ((size_t)(b * NL + c) * NH + h) * 16;
    float4 kc[16];
#pragma unroll
    for (int i = 0; i < 16; ++i) kc[i] = kv[i];

    float* srow = scores + (size_t)bh * NUTOP * NL + c;
    for (int r = 0; r < NUTOP; ++r) {
        float s = 0.0f;
#pragma unroll
        for (int i = 0; i < 16; ++i) {
            const float4 qq = qs[r][i];
            s += qq.x * kc[i].x + qq.y * kc[i].y + qq.z * kc[i].z + qq.w * kc[i].w;
        }
        srow[(size_t)r * NL] = s * 0.125f;   // 1/sqrt(64)
    }
}

// ---------------------------------------------------------------------------
// K3b: main write tide. Zero duty is GRID-STRIDED over zone-3 (fill-kernel
// pattern): thread g stores f4 at g + s*G3, s=0..7; G3 is a multiple of 512
// so the containing row (and the rowmap skip) is wave-uniform. Attn duty
// (normalize one row from ws scores) is SPREAD across the grid at
// block%10==2 instead of clustered at the dispatch head.
// ---------------------------------------------------------------------------
__global__ __launch_bounds__(256) void k_zero_attn(
    const int* __restrict__ rowmap, const int* __restrict__ Mtop,
    const float* __restrict__ scores, float* __restrict__ out)
{
    const int t = threadIdx.x;

    // ---- zero duty: 8 grid-strided f4 stores, rowmap-skipped ----
    {
        const int g = blockIdx.x * 256 + t;
        vfloat4* base = (vfloat4*)out + (size_t)Z1ROWS * 512;
        const vfloat4 z = (vfloat4)(0.0f);
#pragma unroll
        for (int s = 0; s < 8; ++s) {
            const int p = g + s * G3;
            const int row = p >> 9;                 // wave-uniform
            if (!rowmap[Z1ROWS + row]) base[p] = z;
        }
    }

    // ---- attn duty, spread: blocks 2, 12, 22, ... carry task block/10 ----
    if (blockIdx.x % 10 == 2) {
        const int a = blockIdx.x / 10;
        if (a < NATTN) {
            __shared__ float redm[4];
            __shared__ float reds[4];
            const int bh   = a / NUTOP;
            const int ui   = a % NUTOP;
            const int row  = Mtop[bh * NUTOP + ui];
            const int lane = t & 63;
            const int wid  = t >> 6;

            const float* srow = scores + ((size_t)bh * NUTOP + ui) * NL;
            float sc[8];
            float mx = -INFINITY;
#pragma unroll
            for (int j = 0; j < 8; ++j) {
                sc[j] = srow[t + 256 * j];
                mx = fmaxf(mx, sc[j]);
            }
#pragma unroll
            for (int off = 1; off < 64; off <<= 1) mx = fmaxf(mx, __shfl_xor(mx, off));
            if (lane == 0) redm[wid] = mx;
            __syncthreads();
            mx = fmaxf(fmaxf(redm[0], redm[1]), fmaxf(redm[2], redm[3]));

            float lsum = 0.0f;
#pragma unroll
            for (int j = 0; j < 8; ++j) {
                sc[j] = __expf(sc[j] - mx);
                lsum += sc[j];
            }
#pragma unroll
            for (int off = 1; off < 64; off <<= 1) lsum += __shfl_xor(lsum, off);
            if (lane == 0) reds[wid] = lsum;
            __syncthreads();
            const float inv = 1.0f / (reds[0] + reds[1] + reds[2] + reds[3]);

            float* orow = out + ((size_t)bh * NL + row) * NL;
#pragma unroll
            for (int j = 0; j < 8; ++j) orow[t + 256 * j] = sc[j] * inv;
        }
    }
}

extern "C" void kernel_launch(void* const* d_in, const int* in_sizes, int n_in,
                              void* d_out, int out_size, void* d_ws, size_t ws_size,
                              hipStream_t stream) {
    const float* q   = (const float*)d_in[0];
    const float* k   = (const float*)d_in[1];
    const int*   idx = (const int*)d_in[2];
    float* out = (float*)d_out;

    float* Mws    = (float*)d_ws;                               // @0       256 KiB
    int*   rowmap = (int*)((char*)d_ws + (256 << 10));          // @256 KiB 256 KiB
    int*   Mtop   = (int*)((char*)d_ws + (512 << 10));          // @512 KiB   5 KiB
    float* scores = (float*)((char*)d_ws + (1 << 20));          // @1 MiB    10 MiB

    k_compute_M_zero<<<NROWS / 4, 256, 0, stream>>>(q, k, idx, Mws, out);
    k_topk<<<NB * NH, 256, 0, stream>>>(Mws, rowmap, Mtop);
    k_scores<<<NB * NH * 8, 256, 0, stream>>>(q, k, Mtop, scores);
    k_zero_attn<<<K3BLK, 256, 0, stream>>>(rowmap, Mtop, scores, out);
}

// Round 11
// 340.050 us; speedup vs baseline: 1.3131x; 1.0002x over previous
//
#include <hip/hip_runtime.h>
#include <math.h>

#define NB 4
#define NL 2048
#define NH 8
#define ND 64
#define NUPART 80
#define NUTOP 40
#define NROWS (NB * NH * NL)        // 65536 output rows
#define NATTN (NB * NH * NUTOP)     // 1280 selected rows

#define ZA_ROWS 10240               // zone A: zeroed by K1   (80 MiB)
#define ZB_ROWS 1536                // zone B: zeroed by K2'  (12 MiB)
#define ZC_ROWS 1536                // zone C: zeroed by K3a' (12 MiB)
#define ZD_BASE (ZA_ROWS + ZB_ROWS + ZC_ROWS)   // 13312
#define ZD_ROWS (NROWS - ZD_BASE)   // 52224 rows: zone D, K3b (408 MiB)

#define ZA_F4 (ZA_ROWS * 512)       // 5,242,880
#define K1_THREADS (16384 * 256)    // 4,194,304
#define K3B_BLOCKS 13056            // ZD_ROWS*512/8/256
#define G3 (K3B_BLOCKS * 256)       // 3,342,336 (multiple of 512)

typedef float vfloat4 __attribute__((ext_vector_type(4)));

// ---------------------------------------------------------------------------
// K1: same-wave fused: one wave per (b,h,l) computes M = max - sum/L over 80
// sampled keys; zero duty = grid-strided fill of zone A (fill-kernel store
// pattern, 1-2 dwordx4 per thread).
// ---------------------------------------------------------------------------
__global__ __launch_bounds__(256) void k_compute_M_zero(
    const float* __restrict__ q, const float* __restrict__ k,
    const int* __restrict__ idx, float* __restrict__ M,
    float* __restrict__ out)
{
    const int t = threadIdx.x;

    // ---- zero duty: grid-stride over zone-A float4s ----
    {
        const int g = blockIdx.x * 256 + t;
        vfloat4* o = (vfloat4*)out;
        const vfloat4 z = (vfloat4)(0.0f);
        o[g] = z;
        const int g2 = g + K1_THREADS;
        if (g2 < ZA_F4) o[g2] = z;
    }

    // ---- M computation: one wave per (b,h,l) ----
    const int w    = blockIdx.x * 4 + (t >> 6);   // (b*H+h)*L + l
    const int lane = t & 63;
    const int l    = w & (NL - 1);
    const int bh   = w >> 11;
    const int h    = bh & (NH - 1);
    const int b    = bh >> 3;
    const int sl   = lane >> 2;   // sample slot 0..15
    const int dg   = lane & 3;    // d-group 0..3
    const int d0   = dg * 16;

    const float4* qv = (const float4*)(q + (((size_t)(b * NL + l) * NH + h) * ND + d0));
    const float4 q0 = qv[0], q1 = qv[1], q2 = qv[2], q3 = qv[3];

    float mx = -INFINITY, sm = 0.0f;
#pragma unroll
    for (int r = 0; r < 5; ++r) {
        const int s  = r * 16 + sl;
        const int ki = idx[l * NUPART + s];
        const float4* kv = (const float4*)(k + (((size_t)(b * NL + ki) * NH + h) * ND + d0));
        const float4 k0 = kv[0], k1 = kv[1], k2 = kv[2], k3 = kv[3];
        float p = q0.x * k0.x + q0.y * k0.y + q0.z * k0.z + q0.w * k0.w
                + q1.x * k1.x + q1.y * k1.y + q1.z * k1.z + q1.w * k1.w
                + q2.x * k2.x + q2.y * k2.y + q2.z * k2.z + q2.w * k2.w
                + q3.x * k3.x + q3.y * k3.y + q3.z * k3.z + q3.w * k3.w;
        p += __shfl_xor(p, 1);
        p += __shfl_xor(p, 2);
        mx = fmaxf(mx, p);
        sm += p;
    }
#pragma unroll
    for (int m = 4; m < 64; m <<= 1) {
        mx = fmaxf(mx, __shfl_xor(mx, m));
        sm += __shfl_xor(sm, m);
    }
    if (lane == 0) M[w] = mx - sm * (1.0f / (float)NL);
}

// ---------------------------------------------------------------------------
// K2': blocks [0,32): per-(b,h) top-40 (iterative argmax, lower index wins
// ties) -> Mtop + rowmap. Blocks [32, 3104): zero zone B (12 MiB) so the
// write tide keeps running while topk computes.
// ---------------------------------------------------------------------------
__global__ __launch_bounds__(256) void k_topk_zero(
    const float* __restrict__ M, int* __restrict__ rowmap,
    int* __restrict__ Mtop, float* __restrict__ out)
{
    const int t = threadIdx.x;

    if (blockIdx.x >= NB * NH) {
        const int g = (blockIdx.x - NB * NH) * 256 + t;
        vfloat4* o = (vfloat4*)out + (size_t)ZA_ROWS * 512 + g;
        *o = (vfloat4)(0.0f);
        return;
    }

    __shared__ float sM[NL];
    __shared__ float rv[4];
    __shared__ int   ri[4];
    const int bh = blockIdx.x;

    for (int j = t; j < NL; j += 256) {
        sM[j] = M[bh * NL + j];
        rowmap[bh * NL + j] = 0;
    }
    __syncthreads();

    for (int it = 0; it < NUTOP; ++it) {
        float v = -INFINITY;
        int   i = NL;
        for (int j = t; j < NL; j += 256) {
            const float m = sM[j];
            if (m > v || (m == v && j < i)) { v = m; i = j; }
        }
#pragma unroll
        for (int off = 1; off < 64; off <<= 1) {
            const float ov = __shfl_xor(v, off);
            const int   oi = __shfl_xor(i, off);
            if (ov > v || (ov == v && oi < i)) { v = ov; i = oi; }
        }
        const int wid = t >> 6;
        if ((t & 63) == 0) { rv[wid] = v; ri[wid] = i; }
        __syncthreads();
        if (t == 0) {
            for (int w2 = 1; w2 < 4; ++w2) {
                if (rv[w2] > v || (rv[w2] == v && ri[w2] < i)) { v = rv[w2]; i = ri[w2]; }
            }
            Mtop[bh * NUTOP + it] = i;
            rowmap[bh * NL + i] = 1;
            sM[i] = -INFINITY;
        }
        __syncthreads();
    }
}

// ---------------------------------------------------------------------------
// K3a': blocks [0,256): scores (32 bh x 8 col-tiles; 40 q-rows in LDS, one
// K column per thread, K read once per bh); raw scaled scores -> d_ws.
// Blocks [256, 3328): zero zone C (12 MiB) to keep the tide running.
// ---------------------------------------------------------------------------
__global__ __launch_bounds__(256) void k_scores_zero(
    const float* __restrict__ q, const float* __restrict__ k,
    const int* __restrict__ Mtop, float* __restrict__ scores,
    float* __restrict__ out)
{
    const int t = threadIdx.x;

    if (blockIdx.x >= 256) {
        const int g = (blockIdx.x - 256) * 256 + t;
        vfloat4* o = (vfloat4*)out + ((size_t)ZA_ROWS + ZB_ROWS) * 512 + g;
        *o = (vfloat4)(0.0f);
        return;
    }

    __shared__ float4 qs[NUTOP][16];
    __shared__ int    rows[NUTOP];

    const int bh = blockIdx.x >> 3;
    const int ct = blockIdx.x & 7;
    const int b  = bh >> 3;
    const int h  = bh & 7;

    if (t < NUTOP) rows[t] = Mtop[bh * NUTOP + t];
    __syncthreads();
    for (int i = t; i < NUTOP * 16; i += 256) {
        const int r = i >> 4, d = i & 15;
        qs[r][d] = ((const float4*)q)[((size_t)(b * NL + rows[r]) * NH + h) * 16 + d];
    }
    __syncthreads();

    const int c = ct * 256 + t;
    const float4* kv = (const float4*)k + ((size_t)(b * NL + c) * NH + h) * 16;
    float4 kc[16];
#pragma unroll
    for (int i = 0; i < 16; ++i) kc[i] = kv[i];

    float* srow = scores + (size_t)bh * NUTOP * NL + c;
    for (int r = 0; r < NUTOP; ++r) {
        float s = 0.0f;
#pragma unroll
        for (int i = 0; i < 16; ++i) {
            const float4 qq = qs[r][i];
            s += qq.x * kc[i].x + qq.y * kc[i].y + qq.z * kc[i].z + qq.w * kc[i].w;
        }
        srow[(size_t)r * NL] = s * 0.125f;   // 1/sqrt(64)
    }
}

// ---------------------------------------------------------------------------
// K3b: main write tide over zone D. Grid-strided zero duty (8 dwordx4 per
// thread, wave-uniform row for the rowmap skip); attn-normalize duty spread
// across the grid at block%10==2 (read 8 KiB ws scores, block softmax,
// write the 2048-wide row).
// ---------------------------------------------------------------------------
__global__ __launch_bounds__(256) void k_zero_attn(
    const int* __restrict__ rowmap, const int* __restrict__ Mtop,
    const float* __restrict__ scores, float* __restrict__ out)
{
    const int t = threadIdx.x;

    // ---- zero duty: 8 grid-strided f4 stores, rowmap-skipped ----
    {
        const int g = blockIdx.x * 256 + t;
        vfloat4* base = (vfloat4*)out + (size_t)ZD_BASE * 512;
        const vfloat4 z = (vfloat4)(0.0f);
#pragma unroll
        for (int s = 0; s < 8; ++s) {
            const int p = g + s * G3;
            const int row = p >> 9;                 // wave-uniform
            if (!rowmap[ZD_BASE + row]) base[p] = z;
        }
    }

    // ---- attn duty, spread: blocks 2, 12, 22, ... carry task block/10 ----
    if (blockIdx.x % 10 == 2) {
        const int a = blockIdx.x / 10;
        if (a < NATTN) {
            __shared__ float redm[4];
            __shared__ float reds[4];
            const int bh   = a / NUTOP;
            const int ui   = a % NUTOP;
            const int row  = Mtop[bh * NUTOP + ui];
            const int lane = t & 63;
            const int wid  = t >> 6;

            const float* srow = scores + ((size_t)bh * NUTOP + ui) * NL;
            float sc[8];
            float mx = -INFINITY;
#pragma unroll
            for (int j = 0; j < 8; ++j) {
                sc[j] = srow[t + 256 * j];
                mx = fmaxf(mx, sc[j]);
            }
#pragma unroll
            for (int off = 1; off < 64; off <<= 1) mx = fmaxf(mx, __shfl_xor(mx, off));
            if (lane == 0) redm[wid] = mx;
            __syncthreads();
            mx = fmaxf(fmaxf(redm[0], redm[1]), fmaxf(redm[2], redm[3]));

            float lsum = 0.0f;
#pragma unroll
            for (int j = 0; j < 8; ++j) {
                sc[j] = __expf(sc[j] - mx);
                lsum += sc[j];
            }
#pragma unroll
            for (int off = 1; off < 64; off <<= 1) lsum += __shfl_xor(lsum, off);
            if (lane == 0) reds[wid] = lsum;
            __syncthreads();
            const float inv = 1.0f / (reds[0] + reds[1] + reds[2] + reds[3]);

            float* orow = out + ((size_t)bh * NL + row) * NL;
#pragma unroll
            for (int j = 0; j < 8; ++j) orow[t + 256 * j] = sc[j] * inv;
        }
    }
}

extern "C" void kernel_launch(void* const* d_in, const int* in_sizes, int n_in,
                              void* d_out, int out_size, void* d_ws, size_t ws_size,
                              hipStream_t stream) {
    const float* q   = (const float*)d_in[0];
    const float* k   = (const float*)d_in[1];
    const int*   idx = (const int*)d_in[2];
    float* out = (float*)d_out;

    float* Mws    = (float*)d_ws;                               // @0       256 KiB
    int*   rowmap = (int*)((char*)d_ws + (256 << 10));          // @256 KiB 256 KiB
    int*   Mtop   = (int*)((char*)d_ws + (512 << 10));          // @512 KiB   5 KiB
    float* scores = (float*)((char*)d_ws + (1 << 20));          // @1 MiB    10 MiB

    k_compute_M_zero<<<NROWS / 4, 256, 0, stream>>>(q, k, idx, Mws, out);
    k_topk_zero<<<NB * NH + 3072, 256, 0, stream>>>(Mws, rowmap, Mtop, out);
    k_scores_zero<<<256 + 3072, 256, 0, stream>>>(q, k, Mtop, scores, out);
    k_zero_attn<<<K3B_BLOCKS, 256, 0, stream>>>(rowmap, Mtop, scores, out);
}